// Round 14
// baseline (180.551 us; speedup 1.0000x reference)
//
#include <hip/hip_runtime.h>
#include <utility>

// Gaunt tensor product via exact collapse of the S2-grid path to a sparse
// packed Gaunt tensor (computed on-device from Y_in/Y_out/qw).
//
// K0: per (i,j): G_row[k] = sum_p qw*Y_out[k,p]*Y_in[i,p]*Y_in[j,p],
//     packed + pre-scaled by 1/64.
// K1 (fused): grid (512, 3); block = 4 n x 1 branch, 256 thr, wave = n.
//     Lane = (c_q = lane&15 -> 4 channels, m_s = lane>>4 -> 16 m's).
//     x staged PADDED (20-float rows) via per-lane-src global_load_lds,
//     read as ds_read_b128 (4 distinct addrs/instr, 16-way multicast,
//     conflict-free). W per-lane dwordx4 from L2. m-reduction via
//     shfl_xor butterfly (lanes 16/32 apart). Gaunt in registers.
//     Mix + coalesced store via per-wave LDS (R9 path).

#define NN 2048

__host__ __device__ constexpr int l_of9(int i)  { return i < 1 ? 0 : (i < 4 ? 1 : 2); }
__host__ __device__ constexpr int l_of25(int k) { return k < 1 ? 0 : (k < 4 ? 1 : (k < 9 ? 2 : (k < 16 ? 3 : 4))); }
__host__ __device__ constexpr int iabs_(int v)  { return v < 0 ? -v : v; }

__host__ __device__ constexpr bool gmask(int k, int i, int j) {
    const int l3 = l_of25(k), m3 = k - l3 * l3 - l3;
    const int l1 = l_of9(i),  m1 = i - l1 * l1 - l1;
    const int l2 = l_of9(j),  m2 = j - l2 * l2 - l2;
    if (((l1 + l2 + l3) & 1) != 0) return false;
    if (l3 > l1 + l2 || l3 < iabs_(l1 - l2)) return false;
    const int am3 = iabs_(m3);
    return (am3 == iabs_(m1 + m2)) || (am3 == iabs_(m1 - m2));
}

struct GTab {
    int po[82];
    int pc[81];
    int kl[81][12];
    constexpr GTab() : po{}, pc{}, kl{} {
        int off = 0;
        for (int ij = 0; ij < 81; ++ij) {
            po[ij] = off;
            const int i = ij / 9, j = ij % 9;
            int cnum = 0;
            for (int k = 0; k < 25; ++k)
                if (gmask(k, i, j)) kl[ij][cnum++] = k;
            pc[ij] = cnum;
            off += (cnum + 3) & ~3;
        }
        po[81] = off;
    }
};
constexpr GTab GT{};

// ---------------------------------------------------------------------------
// K0: compute + pack G (pre-scaled by 1/64). Grid 81, 256 threads.
// ---------------------------------------------------------------------------
__global__ __launch_bounds__(256) void gaunt_pack_kernel(
    const float* __restrict__ Y_in, const float* __restrict__ Y_out,
    const float* __restrict__ qw, float* __restrict__ gp)
{
    const int ij = blockIdx.x;
    const int i = ij / 9, j = ij % 9;
    const int t = threadIdx.x;

    __shared__ float yy[780];
    __shared__ float ps[25][8];
    __shared__ float gr[25];

    for (int p = t; p < 780; p += 256)
        yy[p] = Y_in[i * 780 + p] * Y_in[j * 780 + p] * qw[p / 39];
    __syncthreads();

    if (t < 200) {
        const int k = t >> 3, s = t & 7;
        const float* yo = Y_out + k * 780;
        const int p1 = (s * 98 + 98 < 780) ? (s * 98 + 98) : 780;
        float a = 0.f;
        for (int p = s * 98; p < p1; ++p) a = fmaf(yy[p], yo[p], a);
        ps[k][s] = a;
    }
    __syncthreads();

    if (t < 25) {
        float a = 0.f;
#pragma unroll
        for (int s = 0; s < 8; ++s) a += ps[t][s];
        gr[t] = a;
    }
    __syncthreads();

    const int cntp = (GT.pc[ij] + 3) & ~3;
    if (t < cntp)
        gp[GT.po[ij] + t] = (t < GT.pc[ij]) ? gr[GT.kl[ij][t]] * 0.015625f : 0.f;
}

// ---------------------------------------------------------------------------
// Sparse in-register Gaunt with compile-time indices (gp loads uniform).
// ---------------------------------------------------------------------------
template <int IJ, int... Ts>
__device__ __forceinline__ void gaunt_apply(const float (&g)[12], float pij,
    float (&cov)[25], std::integer_sequence<int, Ts...>)
{
    ((cov[GT.kl[IJ][Ts]] = fmaf(g[Ts], pij, cov[GT.kl[IJ][Ts]])), ...);
}

template <int IJ>
__device__ __forceinline__ void gaunt_pair(const float* __restrict__ gp,
    const float (&c1)[9], const float (&c2)[9], float (&cov)[25])
{
    constexpr int cnt = GT.pc[IJ];
    if constexpr (cnt > 0) {
        constexpr int base = GT.po[IJ];
        constexpr int nv = (cnt + 3) / 4;
        const float pij = c1[IJ / 9] * c2[IJ % 9];
        float g[12];
#pragma unroll
        for (int q = 0; q < nv; ++q) {
            const float4 v = ((const float4*)(gp + base))[q];
            g[4 * q] = v.x; g[4 * q + 1] = v.y; g[4 * q + 2] = v.z; g[4 * q + 3] = v.w;
        }
        gaunt_apply<IJ>(g, pij, cov, std::make_integer_sequence<int, cnt>{});
    }
}

template <int I, int... Js>
__device__ __forceinline__ void gaunt_row(const float* __restrict__ gp,
    const float (&c1)[9], const float (&c2)[9], float (&cov)[25],
    std::integer_sequence<int, Js...>)
{
    (gaunt_pair<I * 9 + Js>(gp, c1, c2, cov), ...);
    __builtin_amdgcn_sched_barrier(0);   // bound live ranges per row
}

template <int... Is>
__device__ __forceinline__ void gaunt_all(const float* __restrict__ gp,
    const float (&c1)[9], const float (&c2)[9], float (&cov)[25],
    std::integer_sequence<int, Is...>)
{
    (gaunt_row<Is>(gp, c1, c2, cov, std::make_integer_sequence<int, 9>{}), ...);
}

// ---------------------------------------------------------------------------
// global_load_lds helper: 16B per lane, dest = uniform base + lane*16.
// ---------------------------------------------------------------------------
typedef __attribute__((address_space(1))) const unsigned int gas_u32;
typedef __attribute__((address_space(3))) unsigned int las_u32;
__device__ __forceinline__ void gll16(const void* g, void* l) {
    __builtin_amdgcn_global_load_lds((gas_u32*)g, (las_u32*)l, 16, 0, 0);
}

// ---------------------------------------------------------------------------
// K1. LDS x layout per (n_l, arr): [mi(16)][m_s(4)][20 floats] (80B rows).
//   row r = mi*4+m_s holds m = m_s*16+mi; slots 0..15 = comps 0..15,
//   slots 16..19 = comps 14..17 (src re-read at +14; never OOB).
// Stage groups: G in [0,2560): n_l=G/640, arr=(G%640)/320, g=G%320,
//   r=g/5, gs=g%5, src_s = gs==4 ? 14 : gs*4.
// ---------------------------------------------------------------------------
template <int E1, int E2>
__device__ __forceinline__ void k1_body(
    const float* __restrict__ x1, const float* __restrict__ x2,
    const float* __restrict__ W1, const float* __restrict__ W2,
    const float* __restrict__ Wout, const float* __restrict__ gp,
    float* __restrict__ out, float* smemf, int b)
{
    const int t    = threadIdx.x;
    const int lane = t & 63;
    const int w    = t >> 6;
    const int c_q  = lane & 15;
    const int m_s  = lane >> 4;
    const int n0   = blockIdx.x * 4;
    const int n    = n0 + w;

    // ---- stage all 64 m of 4 n x 2 arrays, padded rows ----
    char* smem = (char*)smemf;
#pragma unroll
    for (int i = 0; i < 10; ++i) {
        const int G   = i * 256 + t;
        const int n_l = G / 640;
        const int rem = G - n_l * 640;
        const int arr = rem / 320;
        const int g   = rem - arr * 320;
        const int r   = g / 5;
        const int gs  = g - r * 5;
        const int mi  = r >> 2;
        const int msl = r & 3;
        const int m   = msl * 16 + mi;
        const int ss  = (gs == 4) ? 14 : gs * 4;
        const float* src = (arr ? x2 : x1) + (size_t)(n0 + n_l) * 1152 + m * 18 + ss;
        char* dst = smem + (i * 256 + (t & ~63)) * 16;   // uniform base
        gll16(src, dst);
    }
    __syncthreads();

    // ---- projection: lane owns 4 c (c_q*4..+3) and 16 m (m_s slice) ----
    const float* xb1 = smemf + w * 2560;
    const float* xb2 = xb1 + 1280;

    float a1[4][9], a2[4][9];
#pragma unroll
    for (int cg = 0; cg < 4; ++cg)
#pragma unroll
        for (int i = 0; i < 9; ++i) { a1[cg][i] = 0.f; a2[cg][i] = 0.f; }

    union F4 { float4 v; float f[4]; };

#pragma unroll 1
    for (int mi = 0; mi < 16; ++mi) {
        const int m = m_s * 16 + mi;
        const float* r1 = xb1 + (mi * 4 + m_s) * 20;
        const float* r2 = xb2 + (mi * 4 + m_s) * 20;

        float cx1[18], cx2[18];
#pragma unroll
        for (int q = 0; q < 4; ++q) {
            const float4 u1 = *(const float4*)(r1 + q * 4);
            const float4 u2 = *(const float4*)(r2 + q * 4);
            cx1[4*q] = u1.x; cx1[4*q+1] = u1.y; cx1[4*q+2] = u1.z; cx1[4*q+3] = u1.w;
            cx2[4*q] = u2.x; cx2[4*q+1] = u2.y; cx2[4*q+2] = u2.z; cx2[4*q+3] = u2.w;
        }
        {
            const float4 u1 = *(const float4*)(r1 + 16);
            const float4 u2 = *(const float4*)(r2 + 16);
            cx1[16] = u1.z; cx1[17] = u1.w;
            cx2[16] = u2.z; cx2[17] = u2.w;
        }

        F4 w1q[3], w2q[3];
#pragma unroll
        for (int l = 0; l < 3; ++l) {
            const size_t o = ((size_t)((b * 3 + l) * 64 + m)) * 64 + c_q * 4;
            w1q[l].v = *(const float4*)(W1 + o);
            w2q[l].v = *(const float4*)(W2 + o);
        }

#pragma unroll
        for (int l = 0; l < 3; ++l) {
            const int O1 = ((l & 1) ^ E1) * 9 + l * l;
            const int O2 = ((l & 1) ^ E2) * 9 + l * l;
#pragma unroll
            for (int cg = 0; cg < 4; ++cg)
#pragma unroll
                for (int ii = 0; ii <= 2 * l; ++ii) {
                    a1[cg][l*l+ii] = fmaf(cx1[O1 + ii], w1q[l].f[cg], a1[cg][l*l+ii]);
                    a2[cg][l*l+ii] = fmaf(cx2[O2 + ii], w2q[l].f[cg], a2[cg][l*l+ii]);
                }
        }
    }

    // ---- butterfly reduce over the 4 m-slices (lanes 16/32 apart) ----
#pragma unroll
    for (int cg = 0; cg < 4; ++cg)
#pragma unroll
        for (int i = 0; i < 9; ++i) {
            a1[cg][i] += __shfl_xor(a1[cg][i], 16, 64);
            a1[cg][i] += __shfl_xor(a1[cg][i], 32, 64);
            a2[cg][i] += __shfl_xor(a2[cg][i], 16, 64);
            a2[cg][i] += __shfl_xor(a2[cg][i], 32, 64);
        }

    // ---- static 4-way select: this lane's channel is c_q*4 + m_s ----
    float c1v[9], c2v[9];
#pragma unroll
    for (int i = 0; i < 9; ++i) { c1v[i] = a1[0][i]; c2v[i] = a2[0][i]; }
#pragma unroll
    for (int q = 1; q < 4; ++q) {
        const bool sel = (m_s == q);
#pragma unroll
        for (int i = 0; i < 9; ++i) {
            c1v[i] = sel ? a1[q][i] : c1v[i];
            c2v[i] = sel ? a2[q][i] : c2v[i];
        }
    }
    const int cown = c_q * 4 + m_s;

    // ---- Gaunt in registers (gp pre-scaled by 1/64, uniform s_loads) ----
    float cov[25] = {0,0,0,0,0,0,0,0,0,0,0,0,0,0,0,0,0,0,0,0,0,0,0,0,0};
    gaunt_all(gp, c1v, c2v, cov, std::make_integer_sequence<int, 9>{});

    __syncthreads();   // x region dead for ALL waves -> reuse as colw

    // ---- co exchange + mix, intra-wave ----
    float* colw = smemf + w * 1792;            // [d(64)][28]
#pragma unroll
    for (int k = 0; k < 25; ++k) colw[cown * 28 + k] = cov[k];

    const float* WoB = Wout + (size_t)b * 20480 + cown;
    float acc[25];
#pragma unroll
    for (int k = 0; k < 25; ++k) acc[k] = 0.f;

#pragma unroll 1
    for (int dc = 0; dc < 16; ++dc) {
        float wv[5][4];
#pragma unroll
        for (int l3 = 0; l3 < 5; ++l3)
#pragma unroll
            for (int dd = 0; dd < 4; ++dd)
                wv[l3][dd] = WoB[(l3 * 64 + dc * 4 + dd) * 64];
#pragma unroll
        for (int dd = 0; dd < 4; ++dd) {
            const float* row = colw + (dc * 4 + dd) * 28;
            float f[28];
#pragma unroll
            for (int q = 0; q < 7; ++q) {
                const float4 v = *(const float4*)(row + q * 4);
                f[4*q] = v.x; f[4*q+1] = v.y; f[4*q+2] = v.z; f[4*q+3] = v.w;
            }
#pragma unroll
            for (int k = 0; k < 25; ++k)
                acc[k] = fmaf(f[k], wv[l_of25(k)][dd], acc[k]);
        }
    }

    // ---- restage own-wave region for coalesced stores ----
#pragma unroll
    for (int k = 0; k < 25; ++k) colw[cown * 25 + k] = acc[k] * 0.125f;

    float* on = out + ((size_t)n * 3 + b) * 1600;
#pragma unroll
    for (int r = 0; r < 6; ++r) {
        const float4 v = *(const float4*)&colw[r * 256 + lane * 4];
        *(float4*)&on[r * 256 + lane * 4] = v;
    }
    on[1536 + lane] = colw[1536 + lane];
}

__global__ __launch_bounds__(256, 3) void fused_kernel(
    const float* __restrict__ x1, const float* __restrict__ x2,
    const float* __restrict__ W1, const float* __restrict__ W2,
    const float* __restrict__ Wout, const float* __restrict__ gp,
    float* __restrict__ out)
{
    __shared__ __align__(16) float smemf[10240];   // 40960 B
    const int b = blockIdx.y;
    if (b == 0)      k1_body<0, 0>(x1, x2, W1, W2, Wout, gp, out, smemf, 0);
    else if (b == 1) k1_body<0, 1>(x1, x2, W1, W2, Wout, gp, out, smemf, 1);
    else             k1_body<1, 0>(x1, x2, W1, W2, Wout, gp, out, smemf, 2);
}

extern "C" void kernel_launch(void* const* d_in, const int* in_sizes, int n_in,
                              void* d_out, int out_size, void* d_ws, size_t ws_size,
                              hipStream_t stream) {
    const float* x1    = (const float*)d_in[0];
    const float* x2    = (const float*)d_in[1];
    const float* W1    = (const float*)d_in[2];
    const float* W2    = (const float*)d_in[3];
    const float* Wout  = (const float*)d_in[4];
    const float* Y_in  = (const float*)d_in[5];
    const float* Y_out = (const float*)d_in[6];
    const float* qw    = (const float*)d_in[7];
    float* outp = (float*)d_out;
    float* gp   = (float*)d_ws;

    gaunt_pack_kernel<<<81, 256, 0, stream>>>(Y_in, Y_out, qw, gp);
    fused_kernel<<<dim3(NN / 4, 3), 256, 0, stream>>>(x1, x2, W1, W2, Wout, gp, outp);
}